// Round 1
// baseline (112.757 us; speedup 1.0000x reference)
//
#include <hip/hip_runtime.h>
#include <math.h>

#define NPTS 16384
#define HDIM 64
#define JCH 8
#define CHUNK (NPTS / JCH)   // 2048
#define IBLK 256
#define EPSF 1e-8f
#define FMAX3 3.402823466e38f

// Insert d into sorted triple (m1<=m2<=m3), keeping 3 smallest.
// n1=min(d,m1); n2=med3(d,m1,m2); n3=med3(d,m2,m3). Evaluate in reverse so
// in-place updates read old values.
__device__ __forceinline__ void ins3(float& m1, float& m2, float& m3, float d) {
    m3 = __builtin_amdgcn_fmed3f(d, m2, m3);
    m2 = __builtin_amdgcn_fmed3f(d, m1, m2);
    m1 = fminf(d, m1);
}

// Kernel 1: partial 3-smallest |xi - xj| per i over one j-chunk.
// grid = (NPTS/IBLK) * JCH blocks; block b: ic = b>>3, jc = b&7.
__global__ __launch_bounds__(IBLK) void knn_partial_kernel(
    const float* __restrict__ x, float* __restrict__ part, float* __restrict__ acc) {
    __shared__ float4 sx[CHUNK / 4];
    const int jc = blockIdx.x & (JCH - 1);
    const int ic = blockIdx.x >> 3;
    const float4* xg = (const float4*)(x + jc * CHUNK);
    for (int t = threadIdx.x; t < CHUNK / 4; t += IBLK) sx[t] = xg[t];
    if (blockIdx.x == 0 && threadIdx.x < 4) acc[threadIdx.x] = 0.0f;  // zero accumulators (only block 0; kernel2 runs after)
    __syncthreads();

    const int i = ic * IBLK + threadIdx.x;
    const float xi = x[i];
    // two independent trackers to break the dependency chain
    float a1 = FMAX3, a2 = FMAX3, a3 = FMAX3;
    float c1 = FMAX3, c2 = FMAX3, c3 = FMAX3;
#pragma unroll 4
    for (int k = 0; k < CHUNK / 4; ++k) {
        float4 v = sx[k];  // uniform address -> LDS broadcast, conflict-free
        float d0 = fabsf(xi - v.x);
        float d1 = fabsf(xi - v.y);
        float d2 = fabsf(xi - v.z);
        float d3 = fabsf(xi - v.w);
        ins3(a1, a2, a3, d0);
        ins3(c1, c2, c3, d1);
        ins3(a1, a2, a3, d2);
        ins3(c1, c2, c3, d3);
    }
    ins3(a1, a2, a3, c1);
    ins3(a1, a2, a3, c2);
    ins3(a1, a2, a3, c3);
    part[(jc * 3 + 0) * NPTS + i] = a1;
    part[(jc * 3 + 1) * NPTS + i] = a2;
    part[(jc * 3 + 2) * NPTS + i] = a3;
}

// Kernel 2: merge partial triples -> dens_i; MLP fwd + analytic d2y/dx2;
// wave-reduce and atomically accumulate {sum mse, sum d2^2, sum dens, max dens}.
__global__ __launch_bounds__(64) void fuse_kernel(
    const float* __restrict__ x, const float* __restrict__ tg,
    const float* __restrict__ w1, const float* __restrict__ b1,
    const float* __restrict__ w2, const float* __restrict__ b2,
    const float* __restrict__ part, float* __restrict__ acc) {
    __shared__ float sw1[HDIM], sb1[HDIM], sw2[HDIM], sc[HDIM];
    const int t = threadIdx.x;  // block = exactly one wave of 64
    sw1[t] = w1[t];
    sb1[t] = b1[t];
    sw2[t] = w2[t];
    sc[t] = w2[t] * w1[t] * w1[t];
    __syncthreads();

    const int i = blockIdx.x * 64 + t;

    // merge the 8 partial triples
    float m1 = FMAX3, m2 = FMAX3, m3 = FMAX3;
#pragma unroll
    for (int jc = 0; jc < JCH; ++jc) {
        float p1 = part[(jc * 3 + 0) * NPTS + i];
        float p2 = part[(jc * 3 + 1) * NPTS + i];
        float p3 = part[(jc * 3 + 2) * NPTS + i];
        ins3(m1, m2, m3, p1);
        ins3(m1, m2, m3, p2);
        ins3(m1, m2, m3, p3);
    }
    // knn.mean + EPS = (sum3 + 3*EPS)/3 + EPS = sum3/3 + 2*EPS
    float sum3 = m1 + m2 + m3;
    float dens = 1.0f / (sum3 * (1.0f / 3.0f) + 2.0f * EPSF);

    // MLP: y_i = sum_j w2_j tanh(xi*w1_j + b1_j) + b2
    // d2_i = sum_j w2_j*w1_j^2 * (-2 t (1 - t^2))
    const float xi = x[i];
    float y = b2[0];
    float d2a = 0.0f;
#pragma unroll 8
    for (int j = 0; j < HDIM; ++j) {
        float u = fmaf(xi, sw1[j], sb1[j]);
        float e = __expf(2.0f * u);
        float r = __builtin_amdgcn_rcpf(e + 1.0f);
        float tt = fmaf(-2.0f, r, 1.0f);  // tanh(u)
        y = fmaf(sw2[j], tt, y);
        float s = tt * tt;
        float g = 2.0f * tt * (s - 1.0f);  // -2 t (1-t^2)
        d2a = fmaf(sc[j], g, d2a);
    }
    float diff = y - tg[i];
    float msep = diff * diff;
    float d2sq = d2a * d2a;

    float rs_mse = msep, rs_d2 = d2sq, rs_dn = dens, rmx = dens;
    for (int o = 32; o > 0; o >>= 1) {
        rs_mse += __shfl_down(rs_mse, o);
        rs_d2 += __shfl_down(rs_d2, o);
        rs_dn += __shfl_down(rs_dn, o);
        rmx = fmaxf(rmx, __shfl_down(rmx, o));
    }
    if (t == 0) {
        atomicAdd(&acc[0], rs_mse);
        atomicAdd(&acc[1], rs_d2);
        atomicAdd(&acc[2], rs_dn);
        atomicMax((unsigned int*)&acc[3], __float_as_uint(rmx));  // dens>0 so uint-order == float-order
    }
}

__global__ void finalize_kernel(const float* __restrict__ acc, float* __restrict__ out) {
    float mse = acc[0] * (1.0f / NPTS);
    float md2 = acc[1] * (1.0f / NPTS);
    float dmax = acc[3];  // written as monotone uint bits of a positive float
    float mean_density = (acc[2] * (1.0f / NPTS)) / (dmax + EPSF);
    float mean_w = 1.0f + 0.1f * mean_density;
    float penalty = 0.01f * mean_w * md2;
    out[0] = mse + penalty;
    out[1] = mse;
    out[2] = penalty;
}

extern "C" void kernel_launch(void* const* d_in, const int* in_sizes, int n_in,
                              void* d_out, int out_size, void* d_ws, size_t ws_size,
                              hipStream_t stream) {
    const float* x = (const float*)d_in[0];
    const float* tg = (const float*)d_in[1];
    const float* w1 = (const float*)d_in[2];
    const float* b1 = (const float*)d_in[3];
    const float* w2 = (const float*)d_in[4];
    const float* b2 = (const float*)d_in[5];
    float* out = (float*)d_out;
    float* wsf = (float*)d_ws;
    float* part = wsf;                     // JCH*3*NPTS floats = 1.5 MB
    float* acc = wsf + JCH * 3 * NPTS;     // 4 floats

    hipLaunchKernelGGL(knn_partial_kernel, dim3((NPTS / IBLK) * JCH), dim3(IBLK), 0, stream,
                       x, part, acc);
    hipLaunchKernelGGL(fuse_kernel, dim3(NPTS / 64), dim3(64), 0, stream,
                       x, tg, w1, b1, w2, b2, part, acc);
    hipLaunchKernelGGL(finalize_kernel, dim3(1), dim3(1), 0, stream, acc, out);
}

// Round 2
// 111.767 us; speedup vs baseline: 1.0089x; 1.0089x over previous
//
#include <hip/hip_runtime.h>
#include <math.h>

#define NPTS 16384
#define HDIM 64
#define JCH 16
#define CHUNK (NPTS / JCH)   // 1024
#define IBLK 256
#define EPSF 1e-8f
#define FMAX3 3.402823466e38f

// Insert d into sorted triple (m1<=m2<=m3), keeping 3 smallest.
// Evaluate in reverse so in-place updates read old values.
__device__ __forceinline__ void ins3(float& m1, float& m2, float& m3, float d) {
    m3 = __builtin_amdgcn_fmed3f(d, m2, m3);
    m2 = __builtin_amdgcn_fmed3f(d, m1, m2);
    m1 = fminf(d, m1);
}

// Kernel 1: partial 3-smallest |xi - xj| per i over one j-chunk.
// j-chunk values are wave-uniform -> scalar loads (s_load) on the SMEM pipe,
// no LDS at all. grid = (NPTS/IBLK) * JCH blocks; block b: ic = b>>4, jc = b&15.
__global__ __launch_bounds__(IBLK) void knn_partial_kernel(
    const float* __restrict__ x, float* __restrict__ part, float* __restrict__ acc) {
    const int jc = blockIdx.x & (JCH - 1);
    const int ic = blockIdx.x >> 4;
    if (blockIdx.x == 0 && threadIdx.x < 8) acc[threadIdx.x] = 0.0f;  // zero accumulators+ticket (fuse runs after)

    const int i = ic * IBLK + threadIdx.x;
    const float xi = x[i];
    const float* __restrict__ xc = x + jc * CHUNK;  // uniform base
    // two independent trackers to break the dependency chain
    float a1 = FMAX3, a2 = FMAX3, a3 = FMAX3;
    float c1 = FMAX3, c2 = FMAX3, c3 = FMAX3;
#pragma unroll 8
    for (int k = 0; k < CHUNK; k += 2) {
        float d0 = fabsf(xi - xc[k]);      // uniform index -> s_load, SGPR operand
        float d1 = fabsf(xi - xc[k + 1]);
        ins3(a1, a2, a3, d0);
        ins3(c1, c2, c3, d1);
    }
    ins3(a1, a2, a3, c1);
    ins3(a1, a2, a3, c2);
    ins3(a1, a2, a3, c3);
    part[(jc * 3 + 0) * NPTS + i] = a1;
    part[(jc * 3 + 1) * NPTS + i] = a2;
    part[(jc * 3 + 2) * NPTS + i] = a3;
}

// Kernel 2: merge partial triples -> dens_i; MLP fwd + analytic d2y/dx2;
// wave-reduce, atomically accumulate, and last block finalizes out[0..2].
__global__ __launch_bounds__(64) void fuse_kernel(
    const float* __restrict__ x, const float* __restrict__ tg,
    const float* __restrict__ w1, const float* __restrict__ b1,
    const float* __restrict__ w2, const float* __restrict__ b2,
    const float* __restrict__ part, float* __restrict__ acc,
    float* __restrict__ out) {
    __shared__ float sw1[HDIM], sb1[HDIM], sw2[HDIM], sc[HDIM];
    const int t = threadIdx.x;  // block = exactly one wave of 64
    sw1[t] = w1[t];
    sb1[t] = b1[t];
    sw2[t] = w2[t];
    sc[t] = w2[t] * w1[t] * w1[t];
    __syncthreads();

    const int i = blockIdx.x * 64 + t;

    // merge the 16 partial triples
    float m1 = FMAX3, m2 = FMAX3, m3 = FMAX3;
#pragma unroll
    for (int jc = 0; jc < JCH; ++jc) {
        float p1 = part[(jc * 3 + 0) * NPTS + i];
        float p2 = part[(jc * 3 + 1) * NPTS + i];
        float p3 = part[(jc * 3 + 2) * NPTS + i];
        ins3(m1, m2, m3, p1);
        ins3(m1, m2, m3, p2);
        ins3(m1, m2, m3, p3);
    }
    // reference knn row includes the self-distance (=0); knn.mean + EPS
    // = (sum3 + 3*EPS)/3 + EPS = sum3/3 + 2*EPS
    float sum3 = m1 + m2 + m3;
    float dens = 1.0f / (sum3 * (1.0f / 3.0f) + 2.0f * EPSF);

    // MLP: y_i = sum_j w2_j tanh(xi*w1_j + b1_j) + b2
    // d2_i = sum_j w2_j*w1_j^2 * (-2 t (1 - t^2))
    const float xi = x[i];
    float y = b2[0];
    float d2a = 0.0f;
#pragma unroll 8
    for (int j = 0; j < HDIM; ++j) {
        float u = fmaf(xi, sw1[j], sb1[j]);
        float e = __expf(2.0f * u);
        float r = __builtin_amdgcn_rcpf(e + 1.0f);
        float tt = fmaf(-2.0f, r, 1.0f);  // tanh(u)
        y = fmaf(sw2[j], tt, y);
        float s = tt * tt;
        float g = 2.0f * tt * (s - 1.0f);  // -2 t (1-t^2)
        d2a = fmaf(sc[j], g, d2a);
    }
    float diff = y - tg[i];
    float msep = diff * diff;
    float d2sq = d2a * d2a;

    float rs_mse = msep, rs_d2 = d2sq, rs_dn = dens, rmx = dens;
    for (int o = 32; o > 0; o >>= 1) {
        rs_mse += __shfl_down(rs_mse, o);
        rs_d2 += __shfl_down(rs_d2, o);
        rs_dn += __shfl_down(rs_dn, o);
        rmx = fmaxf(rmx, __shfl_down(rmx, o));
    }
    if (t == 0) {
        atomicAdd(&acc[0], rs_mse);
        atomicAdd(&acc[1], rs_d2);
        atomicAdd(&acc[2], rs_dn);
        atomicMax((unsigned int*)&acc[3], __float_as_uint(rmx));  // dens>0: uint-order == float-order
        __threadfence();
        unsigned int ticket = atomicAdd((unsigned int*)&acc[4], 1u);
        if (ticket == gridDim.x - 1) {
            // last block: read back via atomic RMW (coherent), finalize
            float s_mse = atomicAdd(&acc[0], 0.0f);
            float s_d2 = atomicAdd(&acc[1], 0.0f);
            float s_dn = atomicAdd(&acc[2], 0.0f);
            float dmax = __uint_as_float(atomicMax((unsigned int*)&acc[3], 0u));
            float mse = s_mse * (1.0f / NPTS);
            float md2 = s_d2 * (1.0f / NPTS);
            float mean_density = (s_dn * (1.0f / NPTS)) / (dmax + EPSF);
            float mean_w = 1.0f + 0.1f * mean_density;
            float penalty = 0.01f * mean_w * md2;
            out[0] = mse + penalty;
            out[1] = mse;
            out[2] = penalty;
        }
    }
}

extern "C" void kernel_launch(void* const* d_in, const int* in_sizes, int n_in,
                              void* d_out, int out_size, void* d_ws, size_t ws_size,
                              hipStream_t stream) {
    const float* x = (const float*)d_in[0];
    const float* tg = (const float*)d_in[1];
    const float* w1 = (const float*)d_in[2];
    const float* b1 = (const float*)d_in[3];
    const float* w2 = (const float*)d_in[4];
    const float* b2 = (const float*)d_in[5];
    float* out = (float*)d_out;
    float* wsf = (float*)d_ws;
    float* part = wsf;                     // JCH*3*NPTS floats = 3 MB
    float* acc = wsf + JCH * 3 * NPTS;     // 8 floats (4 accum + ticket)

    hipLaunchKernelGGL(knn_partial_kernel, dim3((NPTS / IBLK) * JCH), dim3(IBLK), 0, stream,
                       x, part, acc);
    hipLaunchKernelGGL(fuse_kernel, dim3(NPTS / 64), dim3(64), 0, stream,
                       x, tg, w1, b1, w2, b2, part, acc, out);
}